// Round 15
// baseline (192.442 us; speedup 1.0000x reference)
//
#include <hip/hip_runtime.h>
#include <hip/hip_bf16.h>

typedef __attribute__((ext_vector_type(4))) float f32x4;
typedef __attribute__((ext_vector_type(4))) int i32x4;
typedef __attribute__((ext_vector_type(8))) short s16x8;

static constexpr int NB = 2, NH = 12, SEQ = 4096, DM = 768, HD = 64;
static constexpr int ROWS = NB * SEQ;              // 8192
// Q is pre-scaled by SCALE*log2(e) in the QKV epilogue -> scores arrive in log2 domain
static constexpr float QSC = 0.125f * 1.44269504f; // 0.18033688

#define MFMA(a, b, c) __builtin_amdgcn_mfma_f32_16x16x32_bf16((a), (b), (c), 0, 0, 0)

typedef const void __attribute__((address_space(1)))* gas_t;
typedef void __attribute__((address_space(3)))* las_t;

__device__ __forceinline__ short f2bf(float f) {
  union { float f; unsigned u; } v; v.f = f;
  unsigned r = v.u + 0x7fffu + ((v.u >> 16) & 1u);   // round-to-nearest-even
  return (short)(r >> 16);
}

__device__ __forceinline__ float exp2v(float x) {    // raw v_exp_f32 (2^x)
  float r; asm("v_exp_f32 %0, %1" : "=v"(r) : "v"(x)); return r;
}

// ---------- cast fp32 -> bf16, 4-wide ----------
__global__ __launch_bounds__(256) void k_cast4(const float* __restrict__ in,
                                               short* __restrict__ out, int n4) {
  int i = blockIdx.x * 256 + threadIdx.x;
  if (i < n4) {
    float4 v = reinterpret_cast<const float4*>(in)[i];
    short4 o = { f2bf(v.x), f2bf(v.y), f2bf(v.z), f2bf(v.w) };
    reinterpret_cast<short4*>(out)[i] = o;
  }
}

// ---------- LDS-tiled transpose + cast: in [r][c] fp32 -> out [c][r] bf16 ----------
__global__ __launch_bounds__(256) void k_tcast2(const float* __restrict__ in,
                                                short* __restrict__ out, int r, int c) {
  __shared__ short tile[32][33];
  int tpc = c >> 5;                       // tiles per row of input
  int by = blockIdx.x / tpc, bx = blockIdx.x % tpc;
  int tx = threadIdx.x & 31, ty = threadIdx.x >> 5;   // 32 x 8
#pragma unroll
  for (int i = 0; i < 4; ++i)
    tile[ty + i * 8][tx] = f2bf(in[(size_t)(by * 32 + ty + i * 8) * c + bx * 32 + tx]);
  __syncthreads();
#pragma unroll
  for (int i = 0; i < 4; ++i)
    out[(size_t)(bx * 32 + ty + i * 8) * r + by * 32 + tx] = tile[tx][ty + i * 8];
}

// ---------- 128x128-tile 2-phase GEMM core (m97 structure) ----------
__device__ __forceinline__ void gemm128(const short* __restrict__ A,
                                        const short* __restrict__ Bt,
                                        int K, int row0, int col0,
                                        short As[2][4096], short Bs[2][4096],
                                        f32x4 acc[4][4]) {
  int w = threadIdx.x >> 6, l = threadIdx.x & 63;
  int q = l & 15, g = l >> 4;
  int wr = w >> 1, wc = w & 1;
  int sr = w * 16 + (l >> 2);
  int sc = (l & 3) * 8;

#define STG(buf, k0)                                                           \
  {                                                                            \
    _Pragma("unroll")                                                          \
    for (int i = 0; i < 2; ++i) {                                              \
      __builtin_amdgcn_global_load_lds(                                        \
          (gas_t)(A + (size_t)(row0 + i * 64 + sr) * K + (k0) + sc),           \
          (las_t)&As[buf][i * 2048 + w * 512], 16, 0, 0);                      \
      __builtin_amdgcn_global_load_lds(                                        \
          (gas_t)(Bt + (size_t)(col0 + i * 64 + sr) * K + (k0) + sc),          \
          (las_t)&Bs[buf][i * 2048 + w * 512], 16, 0, 0);                      \
    }                                                                          \
  }

  STG(0, 0);
  __syncthreads();
  int cur = 0;
  for (int k0 = 0; k0 < K; k0 += 32) {
    if (k0 + 32 < K) STG(cur ^ 1, k0 + 32);
    s16x8 af[4], bf[4];
#pragma unroll
    for (int m = 0; m < 4; ++m)
      af[m] = *reinterpret_cast<const s16x8*>(&As[cur][(wr * 64 + m * 16 + q) * 32 + g * 8]);
#pragma unroll
    for (int n = 0; n < 4; ++n)
      bf[n] = *reinterpret_cast<const s16x8*>(&Bs[cur][(wc * 64 + n * 16 + q) * 32 + g * 8]);
#pragma unroll
    for (int m = 0; m < 4; ++m)
#pragma unroll
      for (int n = 0; n < 4; ++n)
        acc[m][n] = MFMA(af[m], bf[n], acc[m][n]);
    __syncthreads();
    cur ^= 1;
  }
#undef STG
}

// ---------- QKV GEMM -> Q (pre-scaled), K row-major [bh][n][64], V^T [bh][64][n] ----------
__global__ __launch_bounds__(256) void k_gemm_qkv2(const short* __restrict__ xb,
                                                   const short* __restrict__ wt,  // [2304][768]
                                                   short* __restrict__ qw,
                                                   short* __restrict__ kw,
                                                   short* __restrict__ vtw) {
  __shared__ __align__(16) short As[2][4096], Bs[2][4096];
  int bid = blockIdx.x;                        // 1152 blocks, %8==0
  int swz = (bid & 7) * 144 + (bid >> 3);
  int brow = swz / 18, bcol = swz % 18;
  int row0 = brow * 128, col0 = bcol * 128;
  f32x4 acc[4][4] = {};
  gemm128(xb, wt, DM, row0, col0, As, Bs, acc);

  int w = threadIdx.x >> 6, l = threadIdx.x & 63;
  int q = l & 15, g = l >> 4;
  int wr = w >> 1, wc = w & 1;
  int cb = col0 + wc * 64;
  int which = cb / DM, h = (cb % DM) >> 6;
  int rowb = row0 + wr * 64;
  int b = rowb >> 12;
  int bh = b * NH + h;
#pragma unroll
  for (int m = 0; m < 4; ++m) {
#pragma unroll
    for (int n = 0; n < 4; ++n) {
      int d = n * 16 + q;
      if (which == 2) {
        int nseq = (rowb & 4095) + m * 16 + g * 4;
        short4 ov = { f2bf(acc[m][n][0]), f2bf(acc[m][n][1]),
                      f2bf(acc[m][n][2]), f2bf(acc[m][n][3]) };
        *reinterpret_cast<short4*>(&vtw[((size_t)bh * HD + d) * SEQ + nseq]) = ov;
      } else {
        short* dst = (which == 0) ? qw : kw;
        float sc = (which == 0) ? QSC : 1.f;
#pragma unroll
        for (int r = 0; r < 4; ++r) {
          int nseq = (rowb & 4095) + m * 16 + g * 4 + r;
          dst[((size_t)bh * SEQ + nseq) * HD + d] = f2bf(acc[m][n][r] * sc);
        }
      }
    }
  }
}

// ---------- proj GEMM + bias -> fp32 out ----------
__global__ __launch_bounds__(256) void k_gemm_proj2(const short* __restrict__ aob,
                                                    const short* __restrict__ wt,   // [768][768]
                                                    const float* __restrict__ bias,
                                                    float* __restrict__ out) {
  __shared__ __align__(16) short As[2][4096], Bs[2][4096];
  int bid = blockIdx.x;                        // 384 blocks, %8==0
  int swz = (bid & 7) * 48 + (bid >> 3);
  int brow = swz / 6, bcol = swz % 6;
  int row0 = brow * 128, col0 = bcol * 128;
  f32x4 acc[4][4] = {};
  gemm128(aob, wt, DM, row0, col0, As, Bs, acc);

  int w = threadIdx.x >> 6, l = threadIdx.x & 63;
  int q = l & 15, g = l >> 4;
  int wr = w >> 1, wc = w & 1;
#pragma unroll
  for (int m = 0; m < 4; ++m)
#pragma unroll
    for (int n = 0; n < 4; ++n) {
      int col = col0 + wc * 64 + n * 16 + q;
      float bv = bias[col];
#pragma unroll
      for (int r = 0; r < 4; ++r) {
        int row = row0 + wr * 64 + m * 16 + g * 4 + r;
        out[(size_t)row * DM + col] = acc[m][n][r] + bv;
      }
    }
}

// ---------- flash attention v13: 64 q-rows/wave (LDS reads halve per work) ----------
// LDS pipe is the bottleneck (~87% of elapsed: 192 b128 reads + staging DMA per
// CU-epoch). All K/V LDS reads are q-independent -> 64 q-rows/wave makes the
// same 16 reads/tile serve 2x the work. 4 waves x 64q = 256 q-rows/block,
// 384 blocks. ~200 VGPR -> launch_bounds(256,2); 2 blocks/CU, LDS 64 KiB.
__global__ __launch_bounds__(256, 2) void k_attn13(const short* __restrict__ qw,
                                                   const short* __restrict__ kw,
                                                   const short* __restrict__ vtw,
                                                   short* __restrict__ ao) {
  __shared__ __align__(16) short lds[2][2][4096];   // 32 KiB

  int bid = blockIdx.x;                       // 384 blocks, %8==0
  int swz = (bid & 7) * 48 + (bid >> 3);      // XCD-contiguous
  int bh = swz >> 4;
  int qchunk = swz & 15;

  int w = threadIdx.x >> 6, l = threadIdx.x & 63;
  int q = l & 15, g = l >> 4;

  const short* Kg = kw + (size_t)bh * SEQ * HD;
  const short* Vg = vtw + (size_t)bh * HD * SEQ;

  int ss = (l & 7) ^ (l >> 3) ^ ((w & 1) << 2);
  int rst = w * 8 + (l >> 3);

  int qbase = qchunk * 256 + w * 64;
  s16x8 qf[4][2];                             // [qt][kh]
#pragma unroll
  for (int qt = 0; qt < 4; ++qt)
#pragma unroll
    for (int kh = 0; kh < 2; ++kh)
      qf[qt][kh] = *reinterpret_cast<const s16x8*>(
          qw + ((size_t)bh * SEQ + qbase + qt * 16 + q) * HD + kh * 32 + g * 8);

  // ones A-fragment for the row-sum MFMA: A[0][k]=1 (lanes q==0), else 0
  s16x8 ones;
  {
    short o1 = (q == 0) ? (short)0x3F80 : (short)0;
#pragma unroll
    for (int i = 0; i < 8; ++i) ones[i] = o1;
  }

  f32x4 o[4][4] = {};                         // [qt][dt]
  f32x4 lsa[4] = {};                          // row-sum rides in C-row 0

#define STAGE(buf, t)                                                              \
  {                                                                                \
    int key0 = (t) * 64;                                                           \
    _Pragma("unroll")                                                              \
    for (int i = 0; i < 2; ++i) {                                                  \
      const short* gk = Kg + (size_t)(key0 + i * 32 + rst) * HD + ss * 8;          \
      __builtin_amdgcn_global_load_lds((gas_t)gk,                                  \
          (las_t)&lds[buf][0][i * 2048 + w * 512], 16, 0, 0);                      \
      const short* gv = Vg + (size_t)(i * 32 + rst) * SEQ + key0 + ss * 8;         \
      __builtin_amdgcn_global_load_lds((gas_t)gv,                                  \
          (las_t)&lds[buf][1][i * 2048 + w * 512], 16, 0, 0);                      \
    }                                                                              \
  }

  // one tile: stage (optionally) into NXT, compute from CUR (static), barrier
#define TBODY(CUR, NXT, tt, DO_STAGE)                                              \
  {                                                                                \
    if (DO_STAGE) STAGE(NXT, (tt) + 1);                                            \
    f32x4 s[2][2][4] = {};   /* [c half][ab tile][qt] */                           \
    __builtin_amdgcn_s_setprio(1);                                                 \
    _Pragma("unroll")                                                              \
    for (int c = 0; c < 2; ++c)                                                    \
      _Pragma("unroll")                                                            \
      for (int ab = 0; ab < 2; ++ab) {                                             \
        int R = c * 32 + ab * 4 + ((q >> 2) << 3) + (q & 3);                       \
        int sw = (R & 7) ^ (((R >> 3) & 1) << 2);                                  \
        _Pragma("unroll")                                                          \
        for (int kh = 0; kh < 2; ++kh) {                                           \
          int slot = (kh * 4 + g) ^ sw;                                            \
          s16x8 af = *reinterpret_cast<const s16x8*>(                              \
              &lds[CUR][0][R * 64 + slot * 8]);                                    \
          _Pragma("unroll")                                                        \
          for (int qt = 0; qt < 4; ++qt)                                           \
            s[c][ab][qt] = MFMA(af, qf[qt][kh], s[c][ab][qt]);                     \
        }                                                                          \
      }                                                                            \
    __builtin_amdgcn_s_setprio(0);                                                 \
    i32x4 pv[2][4];          /* packed bf16 P, [c][qt] */                          \
    _Pragma("unroll")                                                              \
    for (int qt = 0; qt < 4; ++qt) {                                               \
      unsigned u[16];                                                              \
      _Pragma("unroll")                                                            \
      for (int i = 0; i < 16; ++i)                                                 \
        u[i] = __float_as_uint(exp2v(s[i >> 3][(i >> 2) & 1][qt][i & 3]));         \
      _Pragma("unroll")                                                            \
      for (int c = 0; c < 2; ++c)                                                  \
        _Pragma("unroll")                                                          \
        for (int j = 0; j < 4; ++j)                                                \
          pv[c][qt][j] = (int)__builtin_amdgcn_perm(u[c * 8 + 2 * j + 1],          \
                                                    u[c * 8 + 2 * j],              \
                                                    0x07060302u);                  \
    }                                                                              \
    __builtin_amdgcn_s_setprio(1);                                                 \
    _Pragma("unroll")                                                              \
    for (int c = 0; c < 2; ++c) {                                                  \
      _Pragma("unroll")                                                            \
      for (int dt = 0; dt < 4; ++dt) {                                             \
        int R = dt * 16 + q;                                                       \
        int sw = (R & 7) ^ (((R >> 3) & 1) << 2);                                  \
        int slot = (c * 4 + g) ^ sw;                                               \
        s16x8 vf = *reinterpret_cast<const s16x8*>(                                \
            &lds[CUR][1][R * 64 + slot * 8]);                                      \
        _Pragma("unroll")                                                          \
        for (int qt = 0; qt < 4; ++qt)                                             \
          o[qt][dt] = MFMA(vf, __builtin_bit_cast(s16x8, pv[c][qt]), o[qt][dt]);   \
      }                                                                            \
      _Pragma("unroll")                                                            \
      for (int qt = 0; qt < 4; ++qt)                                               \
        lsa[qt] = MFMA(ones, __builtin_bit_cast(s16x8, pv[c][qt]), lsa[qt]);       \
    }                                                                              \
    __builtin_amdgcn_s_setprio(0);                                                 \
    __syncthreads();                                                               \
  }

  STAGE(0, 0);
  __syncthreads();

  for (int t = 0; t < SEQ / 64 - 2; t += 2) {
    TBODY(0, 1, t, true);
    TBODY(1, 0, t + 1, true);
  }
  TBODY(0, 1, SEQ / 64 - 2, true);
  TBODY(1, 0, SEQ / 64 - 1, false);
#undef TBODY
#undef STAGE

  // ---- epilogue: broadcast row-sums from lanes (q, g=0) ----
  int b = bh / NH, h = bh % NH;
#pragma unroll
  for (int qt = 0; qt < 4; ++qt) {
    float ls = __shfl(lsa[qt][0], q);
    float inv = 1.f / ls;
    size_t row = (size_t)b * SEQ + qbase + qt * 16 + q;
    short* op = ao + row * DM + h * HD;
#pragma unroll
    for (int dt = 0; dt < 4; ++dt) {
      short4 ov = { f2bf(o[qt][dt][0] * inv), f2bf(o[qt][dt][1] * inv),
                    f2bf(o[qt][dt][2] * inv), f2bf(o[qt][dt][3] * inv) };
      *reinterpret_cast<short4*>(op + dt * 16 + g * 4) = ov;
    }
  }
}

extern "C" void kernel_launch(void* const* d_in, const int* in_sizes, int n_in,
                              void* d_out, int out_size, void* d_ws, size_t ws_size,
                              hipStream_t stream) {
  const float* x      = (const float*)d_in[0];
  const float* w_qkv  = (const float*)d_in[1];
  const float* w_proj = (const float*)d_in[2];
  const float* b_proj = (const float*)d_in[3];
  float* out = (float*)d_out;

  char* p = (char*)d_ws;
  auto take = [&](size_t bytes) { char* r = p; p += (bytes + 255) & ~(size_t)255; return r; };
  short* xb     = (short*)take((size_t)ROWS * DM * 2);
  short* wtqkv  = (short*)take((size_t)3 * DM * DM * 2);
  short* wtproj = (short*)take((size_t)DM * DM * 2);
  short* qw     = (short*)take((size_t)NB * NH * SEQ * HD * 2);
  short* kw     = (short*)take((size_t)NB * NH * SEQ * HD * 2);
  short* vtw    = (short*)take((size_t)NB * NH * HD * SEQ * 2);
  short* ao     = (short*)take((size_t)ROWS * DM * 2);

  int n4 = ROWS * DM / 4;
  k_cast4<<<(n4 + 255) / 256, 256, 0, stream>>>(x, xb, n4);
  k_tcast2<<<(DM / 32) * (3 * DM / 32), 256, 0, stream>>>(w_qkv, wtqkv, DM, 3 * DM);
  k_tcast2<<<(DM / 32) * (DM / 32), 256, 0, stream>>>(w_proj, wtproj, DM, DM);
  k_gemm_qkv2<<<64 * 18, 256, 0, stream>>>(xb, wtqkv, qw, kw, vtw);
  k_attn13<<<NB * NH * (SEQ / 256), 256, 0, stream>>>(qw, kw, vtw, ao);
  k_gemm_proj2<<<64 * 6, 256, 0, stream>>>(ao, wtproj, b_proj, out);
}

// Round 16
// 184.568 us; speedup vs baseline: 1.0427x; 1.0427x over previous
//
#include <hip/hip_runtime.h>
#include <hip/hip_bf16.h>

typedef __attribute__((ext_vector_type(4))) float f32x4;
typedef __attribute__((ext_vector_type(4))) int i32x4;
typedef __attribute__((ext_vector_type(8))) short s16x8;

static constexpr int NB = 2, NH = 12, SEQ = 4096, DM = 768, HD = 64;
static constexpr int ROWS = NB * SEQ;              // 8192
static constexpr int BHROWS = NB * NH * SEQ;       // 98304
// Q is pre-scaled by SCALE*log2(e) in the QKV epilogue -> scores arrive in log2 domain
static constexpr float QSC = 0.125f * 1.44269504f; // 0.18033688

#define MFMA(a, b, c) __builtin_amdgcn_mfma_f32_16x16x32_bf16((a), (b), (c), 0, 0, 0)

typedef const void __attribute__((address_space(1)))* gas_t;
typedef void __attribute__((address_space(3)))* las_t;

__device__ __forceinline__ short f2bf(float f) {
  union { float f; unsigned u; } v; v.f = f;
  unsigned r = v.u + 0x7fffu + ((v.u >> 16) & 1u);   // round-to-nearest-even
  return (short)(r >> 16);
}

__device__ __forceinline__ float exp2v(float x) {    // raw v_exp_f32 (2^x)
  float r; asm("v_exp_f32 %0, %1" : "=v"(r) : "v"(x)); return r;
}

// ---------- cast fp32 -> bf16, 4-wide ----------
__global__ __launch_bounds__(256) void k_cast4(const float* __restrict__ in,
                                               short* __restrict__ out, int n4) {
  int i = blockIdx.x * 256 + threadIdx.x;
  if (i < n4) {
    float4 v = reinterpret_cast<const float4*>(in)[i];
    short4 o = { f2bf(v.x), f2bf(v.y), f2bf(v.z), f2bf(v.w) };
    reinterpret_cast<short4*>(out)[i] = o;
  }
}

// ---------- LDS-tiled transpose + cast: in [r][c] fp32 -> out [c][r] bf16 ----------
__global__ __launch_bounds__(256) void k_tcast2(const float* __restrict__ in,
                                                short* __restrict__ out, int r, int c) {
  __shared__ short tile[32][33];
  int tpc = c >> 5;                       // tiles per row of input
  int by = blockIdx.x / tpc, bx = blockIdx.x % tpc;
  int tx = threadIdx.x & 31, ty = threadIdx.x >> 5;   // 32 x 8
#pragma unroll
  for (int i = 0; i < 4; ++i)
    tile[ty + i * 8][tx] = f2bf(in[(size_t)(by * 32 + ty + i * 8) * c + bx * 32 + tx]);
  __syncthreads();
#pragma unroll
  for (int i = 0; i < 4; ++i)
    out[(size_t)(bx * 32 + ty + i * 8) * r + by * 32 + tx] = tile[tx][ty + i * 8];
}

// ---------- 128x128-tile 2-phase GEMM core (m97 structure) ----------
__device__ __forceinline__ void gemm128(const short* __restrict__ A,
                                        const short* __restrict__ Bt,
                                        int K, int row0, int col0,
                                        short As[2][4096], short Bs[2][4096],
                                        f32x4 acc[4][4]) {
  int w = threadIdx.x >> 6, l = threadIdx.x & 63;
  int q = l & 15, g = l >> 4;
  int wr = w >> 1, wc = w & 1;
  int sr = w * 16 + (l >> 2);
  int sc = (l & 3) * 8;

#define STG(buf, k0)                                                           \
  {                                                                            \
    _Pragma("unroll")                                                          \
    for (int i = 0; i < 2; ++i) {                                              \
      __builtin_amdgcn_global_load_lds(                                        \
          (gas_t)(A + (size_t)(row0 + i * 64 + sr) * K + (k0) + sc),           \
          (las_t)&As[buf][i * 2048 + w * 512], 16, 0, 0);                      \
      __builtin_amdgcn_global_load_lds(                                        \
          (gas_t)(Bt + (size_t)(col0 + i * 64 + sr) * K + (k0) + sc),          \
          (las_t)&Bs[buf][i * 2048 + w * 512], 16, 0, 0);                      \
    }                                                                          \
  }

  STG(0, 0);
  __syncthreads();
  int cur = 0;
  for (int k0 = 0; k0 < K; k0 += 32) {
    if (k0 + 32 < K) STG(cur ^ 1, k0 + 32);
    s16x8 af[4], bf[4];
#pragma unroll
    for (int m = 0; m < 4; ++m)
      af[m] = *reinterpret_cast<const s16x8*>(&As[cur][(wr * 64 + m * 16 + q) * 32 + g * 8]);
#pragma unroll
    for (int n = 0; n < 4; ++n)
      bf[n] = *reinterpret_cast<const s16x8*>(&Bs[cur][(wc * 64 + n * 16 + q) * 32 + g * 8]);
#pragma unroll
    for (int m = 0; m < 4; ++m)
#pragma unroll
      for (int n = 0; n < 4; ++n)
        acc[m][n] = MFMA(af[m], bf[n], acc[m][n]);
    __syncthreads();
    cur ^= 1;
  }
#undef STG
}

// ---------- QKV GEMM -> Q (pre-scaled), K row-major [bh][n][64], V^T [bh][64][n] ----------
__global__ __launch_bounds__(256) void k_gemm_qkv2(const short* __restrict__ xb,
                                                   const short* __restrict__ wt,  // [2304][768]
                                                   short* __restrict__ qw,
                                                   short* __restrict__ kw,
                                                   short* __restrict__ vtw) {
  __shared__ __align__(16) short As[2][4096], Bs[2][4096];
  int bid = blockIdx.x;                        // 1152 blocks, %8==0
  int swz = (bid & 7) * 144 + (bid >> 3);
  int brow = swz / 18, bcol = swz % 18;
  int row0 = brow * 128, col0 = bcol * 128;
  f32x4 acc[4][4] = {};
  gemm128(xb, wt, DM, row0, col0, As, Bs, acc);

  int w = threadIdx.x >> 6, l = threadIdx.x & 63;
  int q = l & 15, g = l >> 4;
  int wr = w >> 1, wc = w & 1;
  int cb = col0 + wc * 64;
  int which = cb / DM, h = (cb % DM) >> 6;
  int rowb = row0 + wr * 64;
  int b = rowb >> 12;
  int bh = b * NH + h;
#pragma unroll
  for (int m = 0; m < 4; ++m) {
#pragma unroll
    for (int n = 0; n < 4; ++n) {
      int d = n * 16 + q;
      if (which == 2) {
        int nseq = (rowb & 4095) + m * 16 + g * 4;
        short4 ov = { f2bf(acc[m][n][0]), f2bf(acc[m][n][1]),
                      f2bf(acc[m][n][2]), f2bf(acc[m][n][3]) };
        *reinterpret_cast<short4*>(&vtw[((size_t)bh * HD + d) * SEQ + nseq]) = ov;
      } else {
        short* dst = (which == 0) ? qw : kw;
        float sc = (which == 0) ? QSC : 1.f;
#pragma unroll
        for (int r = 0; r < 4; ++r) {
          int nseq = (rowb & 4095) + m * 16 + g * 4 + r;
          dst[((size_t)bh * SEQ + nseq) * HD + d] = f2bf(acc[m][n][r] * sc);
        }
      }
    }
  }
}

// ---------- proj GEMM + bias -> fp32 out ----------
__global__ __launch_bounds__(256) void k_gemm_proj2(const short* __restrict__ aob,
                                                    const short* __restrict__ wt,   // [768][768]
                                                    const float* __restrict__ bias,
                                                    float* __restrict__ out) {
  __shared__ __align__(16) short As[2][4096], Bs[2][4096];
  int bid = blockIdx.x;                        // 384 blocks, %8==0
  int swz = (bid & 7) * 48 + (bid >> 3);
  int brow = swz / 6, bcol = swz % 6;
  int row0 = brow * 128, col0 = bcol * 128;
  f32x4 acc[4][4] = {};
  gemm128(aob, wt, DM, row0, col0, As, Bs, acc);

  int w = threadIdx.x >> 6, l = threadIdx.x & 63;
  int q = l & 15, g = l >> 4;
  int wr = w >> 1, wc = w & 1;
#pragma unroll
  for (int m = 0; m < 4; ++m)
#pragma unroll
    for (int n = 0; n < 4; ++n) {
      int col = col0 + wc * 64 + n * 16 + q;
      float bv = bias[col];
#pragma unroll
      for (int r = 0; r < 4; ++r) {
        int row = row0 + wr * 64 + m * 16 + g * 4 + r;
        out[(size_t)row * DM + col] = acc[m][n][r] + bv;
      }
    }
}

// ---------- flash attention v14: 64 q-rows/wave + additive split-K (2 halves) ----------
// R14 proved 64q/wave halves LDS reads (bank-conflict 6.3M->3.1M) but 384
// blocks starved occupancy (1 block/CU -> latency-bound). R12 proved additive
// split-K partials pass replay-revalidation at 768 blocks / ~33% occupancy.
// Combined: 24 bh x 16 qchunks x 2 key-halves = 768 blocks, 32 tiles each.
__global__ __launch_bounds__(256, 2) void k_attn14(const short* __restrict__ qw,
                                                   const short* __restrict__ kw,
                                                   const short* __restrict__ vtw,
                                                   float* __restrict__ opart,
                                                   float* __restrict__ lpart) {
  __shared__ __align__(16) short lds[2][2][4096];   // 32 KiB

  int bid = blockIdx.x;                       // 768 blocks, %8==0
  int swz = (bid & 7) * 96 + (bid >> 3);      // XCD-contiguous
  int bh = swz >> 5;
  int rem = swz & 31;
  int qchunk = rem >> 1;                      // 0..15
  int half = rem & 1;                         // key half

  int w = threadIdx.x >> 6, l = threadIdx.x & 63;
  int q = l & 15, g = l >> 4;

  const short* Kg = kw + (size_t)bh * SEQ * HD;
  const short* Vg = vtw + (size_t)bh * HD * SEQ;

  int ss = (l & 7) ^ (l >> 3) ^ ((w & 1) << 2);
  int rst = w * 8 + (l >> 3);
  int kbase = half * (SEQ / 2);

  int qbase = qchunk * 256 + w * 64;
  s16x8 qf[4][2];                             // [qt][kh]
#pragma unroll
  for (int qt = 0; qt < 4; ++qt)
#pragma unroll
    for (int kh = 0; kh < 2; ++kh)
      qf[qt][kh] = *reinterpret_cast<const s16x8*>(
          qw + ((size_t)bh * SEQ + qbase + qt * 16 + q) * HD + kh * 32 + g * 8);

  // ones A-fragment for the row-sum MFMA: A[0][k]=1 (lanes q==0), else 0
  s16x8 ones;
  {
    short o1 = (q == 0) ? (short)0x3F80 : (short)0;
#pragma unroll
    for (int i = 0; i < 8; ++i) ones[i] = o1;
  }

  f32x4 o[4][4] = {};                         // [qt][dt]
  f32x4 lsa[4] = {};                          // row-sum rides in C-row 0

#define STAGE(buf, t)                                                              \
  {                                                                                \
    int key0 = kbase + (t) * 64;                                                   \
    _Pragma("unroll")                                                              \
    for (int i = 0; i < 2; ++i) {                                                  \
      const short* gk = Kg + (size_t)(key0 + i * 32 + rst) * HD + ss * 8;          \
      __builtin_amdgcn_global_load_lds((gas_t)gk,                                  \
          (las_t)&lds[buf][0][i * 2048 + w * 512], 16, 0, 0);                      \
      const short* gv = Vg + (size_t)(i * 32 + rst) * SEQ + key0 + ss * 8;         \
      __builtin_amdgcn_global_load_lds((gas_t)gv,                                  \
          (las_t)&lds[buf][1][i * 2048 + w * 512], 16, 0, 0);                      \
    }                                                                              \
  }

  // one tile: stage (optionally) into NXT, compute from CUR (static), barrier
#define TBODY(CUR, NXT, tt, DO_STAGE)                                              \
  {                                                                                \
    if (DO_STAGE) STAGE(NXT, (tt) + 1);                                            \
    f32x4 s[2][2][4] = {};   /* [c half][ab tile][qt] */                           \
    __builtin_amdgcn_s_setprio(1);                                                 \
    _Pragma("unroll")                                                              \
    for (int c = 0; c < 2; ++c)                                                    \
      _Pragma("unroll")                                                            \
      for (int ab = 0; ab < 2; ++ab) {                                             \
        int R = c * 32 + ab * 4 + ((q >> 2) << 3) + (q & 3);                       \
        int sw = (R & 7) ^ (((R >> 3) & 1) << 2);                                  \
        _Pragma("unroll")                                                          \
        for (int kh = 0; kh < 2; ++kh) {                                           \
          int slot = (kh * 4 + g) ^ sw;                                            \
          s16x8 af = *reinterpret_cast<const s16x8*>(                              \
              &lds[CUR][0][R * 64 + slot * 8]);                                    \
          _Pragma("unroll")                                                        \
          for (int qt = 0; qt < 4; ++qt)                                           \
            s[c][ab][qt] = MFMA(af, qf[qt][kh], s[c][ab][qt]);                     \
        }                                                                          \
      }                                                                            \
    __builtin_amdgcn_s_setprio(0);                                                 \
    i32x4 pv[2][4];          /* packed bf16 P, [c][qt] */                          \
    _Pragma("unroll")                                                              \
    for (int qt = 0; qt < 4; ++qt) {                                               \
      unsigned u[16];                                                              \
      _Pragma("unroll")                                                            \
      for (int i = 0; i < 16; ++i)                                                 \
        u[i] = __float_as_uint(exp2v(s[i >> 3][(i >> 2) & 1][qt][i & 3]));         \
      _Pragma("unroll")                                                            \
      for (int c = 0; c < 2; ++c)                                                  \
        _Pragma("unroll")                                                          \
        for (int j = 0; j < 4; ++j)                                                \
          pv[c][qt][j] = (int)__builtin_amdgcn_perm(u[c * 8 + 2 * j + 1],          \
                                                    u[c * 8 + 2 * j],              \
                                                    0x07060302u);                  \
    }                                                                              \
    __builtin_amdgcn_s_setprio(1);                                                 \
    _Pragma("unroll")                                                              \
    for (int c = 0; c < 2; ++c) {                                                  \
      _Pragma("unroll")                                                            \
      for (int dt = 0; dt < 4; ++dt) {                                             \
        int R = dt * 16 + q;                                                       \
        int sw = (R & 7) ^ (((R >> 3) & 1) << 2);                                  \
        int slot = (c * 4 + g) ^ sw;                                               \
        s16x8 vf = *reinterpret_cast<const s16x8*>(                                \
            &lds[CUR][1][R * 64 + slot * 8]);                                      \
        _Pragma("unroll")                                                          \
        for (int qt = 0; qt < 4; ++qt)                                             \
          o[qt][dt] = MFMA(vf, __builtin_bit_cast(s16x8, pv[c][qt]), o[qt][dt]);   \
      }                                                                            \
      _Pragma("unroll")                                                            \
      for (int qt = 0; qt < 4; ++qt)                                               \
        lsa[qt] = MFMA(ones, __builtin_bit_cast(s16x8, pv[c][qt]), lsa[qt]);       \
    }                                                                              \
    __builtin_amdgcn_s_setprio(0);                                                 \
    __syncthreads();                                                               \
  }

  STAGE(0, 0);
  __syncthreads();

  for (int t = 0; t < SEQ / 128 - 2; t += 2) {
    TBODY(0, 1, t, true);
    TBODY(1, 0, t + 1, true);
  }
  TBODY(0, 1, SEQ / 128 - 2, true);
  TBODY(1, 0, SEQ / 128 - 1, false);
#undef TBODY
#undef STAGE

  // ---- epilogue: write UNNORMALIZED fp32 partials + row-sums ----
#pragma unroll
  for (int qt = 0; qt < 4; ++qt) {
    float ls = __shfl(lsa[qt][0], q);
    size_t prow = (size_t)bh * SEQ + qbase + qt * 16 + q;
    float* op = opart + ((size_t)half * BHROWS + prow) * HD;
#pragma unroll
    for (int dt = 0; dt < 4; ++dt)
      *reinterpret_cast<f32x4*>(op + dt * 16 + g * 4) = o[qt][dt];
    if (g == 0)
      lpart[(size_t)half * BHROWS + prow] = ls;
  }
}

// ---------- pass2: merge key-half partials -> normalized bf16 ao ----------
__global__ __launch_bounds__(256) void k_merge(const float* __restrict__ opart,
                                               const float* __restrict__ lpart,
                                               short* __restrict__ ao) {
  int i = blockIdx.x * 256 + threadIdx.x;     // one float4 per thread
  if (i >= BHROWS * HD / 4) return;
  int bhn = i >> 4;                           // row (bh*4096+n)
  int d4 = (i & 15) * 4;
  const float* p0 = opart + (size_t)bhn * HD + d4;
  const float* p1 = p0 + (size_t)BHROWS * HD;
  f32x4 a = *reinterpret_cast<const f32x4*>(p0);
  f32x4 b = *reinterpret_cast<const f32x4*>(p1);
  float inv = 1.f / (lpart[bhn] + lpart[BHROWS + bhn]);
  int bh = bhn >> 12, n = bhn & 4095;
  int bb = bh / NH, h = bh % NH;
  short* op = ao + ((size_t)(bb * SEQ + n)) * DM + h * HD + d4;
  short4 ov = { f2bf((a[0] + b[0]) * inv), f2bf((a[1] + b[1]) * inv),
                f2bf((a[2] + b[2]) * inv), f2bf((a[3] + b[3]) * inv) };
  *reinterpret_cast<short4*>(op) = ov;
}

extern "C" void kernel_launch(void* const* d_in, const int* in_sizes, int n_in,
                              void* d_out, int out_size, void* d_ws, size_t ws_size,
                              hipStream_t stream) {
  const float* x      = (const float*)d_in[0];
  const float* w_qkv  = (const float*)d_in[1];
  const float* w_proj = (const float*)d_in[2];
  const float* b_proj = (const float*)d_in[3];
  float* out = (float*)d_out;

  char* p = (char*)d_ws;
  auto take = [&](size_t bytes) { char* r = p; p += (bytes + 255) & ~(size_t)255; return r; };
  short* xb     = (short*)take((size_t)ROWS * DM * 2);
  short* wtqkv  = (short*)take((size_t)3 * DM * DM * 2);
  short* wtproj = (short*)take((size_t)DM * DM * 2);
  short* qw     = (short*)take((size_t)NB * NH * SEQ * HD * 2);
  short* kw     = (short*)take((size_t)NB * NH * SEQ * HD * 2);
  short* vtw    = (short*)take((size_t)NB * NH * HD * SEQ * 2);
  short* ao     = (short*)take((size_t)ROWS * DM * 2);
  float* opart  = (float*)take((size_t)2 * BHROWS * HD * 4);   // 50.3 MB
  float* lpart  = (float*)take((size_t)2 * BHROWS * 4);        // 0.8 MB

  int n4 = ROWS * DM / 4;
  k_cast4<<<(n4 + 255) / 256, 256, 0, stream>>>(x, xb, n4);
  k_tcast2<<<(DM / 32) * (3 * DM / 32), 256, 0, stream>>>(w_qkv, wtqkv, DM, 3 * DM);
  k_tcast2<<<(DM / 32) * (DM / 32), 256, 0, stream>>>(w_proj, wtproj, DM, DM);
  k_gemm_qkv2<<<64 * 18, 256, 0, stream>>>(xb, wtqkv, qw, kw, vtw);
  k_attn14<<<NB * NH * (SEQ / 256) * 2, 256, 0, stream>>>(qw, kw, vtw, opart, lpart);
  k_merge<<<(BHROWS * HD / 4 + 255) / 256, 256, 0, stream>>>(opart, lpart, ao);
  k_gemm_proj2<<<64 * 6, 256, 0, stream>>>(ao, wtproj, b_proj, out);
}

// Round 17
// 177.017 us; speedup vs baseline: 1.0871x; 1.0427x over previous
//
#include <hip/hip_runtime.h>
#include <hip/hip_bf16.h>

typedef __attribute__((ext_vector_type(4))) float f32x4;
typedef __attribute__((ext_vector_type(4))) int i32x4;
typedef __attribute__((ext_vector_type(8))) short s16x8;

static constexpr int NB = 2, NH = 12, SEQ = 4096, DM = 768, HD = 64;
static constexpr int ROWS = NB * SEQ;              // 8192
// Q is pre-scaled by SCALE*log2(e) in the QKV epilogue -> scores arrive in log2 domain
static constexpr float QSC = 0.125f * 1.44269504f; // 0.18033688

#define MFMA(a, b, c) __builtin_amdgcn_mfma_f32_16x16x32_bf16((a), (b), (c), 0, 0, 0)

typedef const void __attribute__((address_space(1)))* gas_t;
typedef void __attribute__((address_space(3)))* las_t;

__device__ __forceinline__ short f2bf(float f) {
  union { float f; unsigned u; } v; v.f = f;
  unsigned r = v.u + 0x7fffu + ((v.u >> 16) & 1u);   // round-to-nearest-even
  return (short)(r >> 16);
}

__device__ __forceinline__ float exp2v(float x) {    // raw v_exp_f32 (2^x)
  float r; asm("v_exp_f32 %0, %1" : "=v"(r) : "v"(x)); return r;
}

// ---------- fused prep: cast x -> bf16, transpose-cast both weight matrices ----------
static constexpr int NC4 = ROWS * DM / 4 / 256;        // 6144 blocks for cast
static constexpr int NT1 = (DM / 32) * (3 * DM / 32);  // 1728 blocks for w_qkv^T
static constexpr int NT2 = (DM / 32) * (DM / 32);      // 576 blocks for w_proj^T

__device__ __forceinline__ void tcast_body(const float* __restrict__ in,
                                           short* __restrict__ out, int r, int c,
                                           int bid, short tile[32][33]) {
  int tpc = c >> 5;
  int by = bid / tpc, bx = bid % tpc;
  int tx = threadIdx.x & 31, ty = threadIdx.x >> 5;   // 32 x 8
#pragma unroll
  for (int i = 0; i < 4; ++i)
    tile[ty + i * 8][tx] = f2bf(in[(size_t)(by * 32 + ty + i * 8) * c + bx * 32 + tx]);
  __syncthreads();
#pragma unroll
  for (int i = 0; i < 4; ++i)
    out[(size_t)(bx * 32 + ty + i * 8) * r + by * 32 + tx] = tile[tx][ty + i * 8];
}

__global__ __launch_bounds__(256) void k_prep(const float* __restrict__ x,
                                              short* __restrict__ xb,
                                              const float* __restrict__ wqkv,
                                              short* __restrict__ wtqkv,
                                              const float* __restrict__ wproj,
                                              short* __restrict__ wtproj) {
  __shared__ short tile[32][33];
  int bid = blockIdx.x;
  if (bid < NC4) {
    int i = bid * 256 + threadIdx.x;
    float4 v = reinterpret_cast<const float4*>(x)[i];
    short4 o = { f2bf(v.x), f2bf(v.y), f2bf(v.z), f2bf(v.w) };
    reinterpret_cast<short4*>(xb)[i] = o;
  } else if (bid < NC4 + NT1) {
    tcast_body(wqkv, wtqkv, DM, 3 * DM, bid - NC4, tile);
  } else {
    tcast_body(wproj, wtproj, DM, DM, bid - NC4 - NT1, tile);
  }
}

// ---------- 128x128-tile 2-phase GEMM core, C^T fragments ----------
// MFMA operand-swapped: thread holds C[row0 + m*16 + q][col0 + n*16 + g*4 + r]
// -> 4 CONSECUTIVE COLUMNS per acc register quad (vectorizable epilogues).
__device__ __forceinline__ void gemm128(const short* __restrict__ A,
                                        const short* __restrict__ Bt,
                                        int K, int row0, int col0,
                                        short As[2][4096], short Bs[2][4096],
                                        f32x4 acc[4][4]) {
  int w = threadIdx.x >> 6, l = threadIdx.x & 63;
  int q = l & 15, g = l >> 4;
  int wr = w >> 1, wc = w & 1;
  int sr = w * 16 + (l >> 2);
  int sc = (l & 3) * 8;

#define STG(buf, k0)                                                           \
  {                                                                            \
    _Pragma("unroll")                                                          \
    for (int i = 0; i < 2; ++i) {                                              \
      __builtin_amdgcn_global_load_lds(                                        \
          (gas_t)(A + (size_t)(row0 + i * 64 + sr) * K + (k0) + sc),           \
          (las_t)&As[buf][i * 2048 + w * 512], 16, 0, 0);                      \
      __builtin_amdgcn_global_load_lds(                                        \
          (gas_t)(Bt + (size_t)(col0 + i * 64 + sr) * K + (k0) + sc),          \
          (las_t)&Bs[buf][i * 2048 + w * 512], 16, 0, 0);                      \
    }                                                                          \
  }

  STG(0, 0);
  __syncthreads();
  int cur = 0;
  for (int k0 = 0; k0 < K; k0 += 32) {
    if (k0 + 32 < K) STG(cur ^ 1, k0 + 32);
    s16x8 af[4], bf[4];
#pragma unroll
    for (int m = 0; m < 4; ++m)
      af[m] = *reinterpret_cast<const s16x8*>(&As[cur][(wr * 64 + m * 16 + q) * 32 + g * 8]);
#pragma unroll
    for (int n = 0; n < 4; ++n)
      bf[n] = *reinterpret_cast<const s16x8*>(&Bs[cur][(wc * 64 + n * 16 + q) * 32 + g * 8]);
#pragma unroll
    for (int m = 0; m < 4; ++m)
#pragma unroll
      for (int n = 0; n < 4; ++n)
        acc[m][n] = MFMA(bf[n], af[m], acc[m][n]);   // swapped: C^T fragments
    __syncthreads();
    cur ^= 1;
  }
#undef STG
}

// ---------- QKV GEMM -> Q (pre-scaled), K row-major [bh][n][64], V^T [bh][64][n] ----------
__global__ __launch_bounds__(256) void k_gemm_qkv2(const short* __restrict__ xb,
                                                   const short* __restrict__ wt,  // [2304][768]
                                                   short* __restrict__ qw,
                                                   short* __restrict__ kw,
                                                   short* __restrict__ vtw) {
  __shared__ __align__(16) short As[2][4096], Bs[2][4096];
  int bid = blockIdx.x;                        // 1152 blocks, %8==0
  int swz = (bid & 7) * 144 + (bid >> 3);
  int brow = swz / 18, bcol = swz % 18;
  int row0 = brow * 128, col0 = bcol * 128;
  f32x4 acc[4][4] = {};
  gemm128(xb, wt, DM, row0, col0, As, Bs, acc);

  int w = threadIdx.x >> 6, l = threadIdx.x & 63;
  int q = l & 15, g = l >> 4;
  int wr = w >> 1, wc = w & 1;
  int cb = col0 + wc * 64;
  int which = cb / DM, h = (cb % DM) >> 6;
  int rowb = row0 + wr * 64;
  int b = rowb >> 12;
  int bh = b * NH + h;
#pragma unroll
  for (int m = 0; m < 4; ++m) {
    int nseq = (rowb & 4095) + m * 16 + q;     // seq row (fixed per m)
#pragma unroll
    for (int n = 0; n < 4; ++n) {
      int d = n * 16 + g * 4;                  // 4 consecutive d in acc[m][n][0..3]
      if (which == 2) {
#pragma unroll
        for (int r = 0; r < 4; ++r)
          vtw[((size_t)bh * HD + d + r) * SEQ + nseq] = f2bf(acc[m][n][r]);
      } else {
        short* dst = (which == 0) ? qw : kw;
        float sc = (which == 0) ? QSC : 1.f;
        short4 ov = { f2bf(acc[m][n][0] * sc), f2bf(acc[m][n][1] * sc),
                      f2bf(acc[m][n][2] * sc), f2bf(acc[m][n][3] * sc) };
        *reinterpret_cast<short4*>(&dst[((size_t)bh * SEQ + nseq) * HD + d]) = ov;
      }
    }
  }
}

// ---------- proj GEMM + bias -> fp32 out (float4 stores) ----------
__global__ __launch_bounds__(256) void k_gemm_proj2(const short* __restrict__ aob,
                                                    const short* __restrict__ wt,   // [768][768]
                                                    const float* __restrict__ bias,
                                                    float* __restrict__ out) {
  __shared__ __align__(16) short As[2][4096], Bs[2][4096];
  int bid = blockIdx.x;                        // 384 blocks, %8==0
  int swz = (bid & 7) * 48 + (bid >> 3);
  int brow = swz / 6, bcol = swz % 6;
  int row0 = brow * 128, col0 = bcol * 128;
  f32x4 acc[4][4] = {};
  gemm128(aob, wt, DM, row0, col0, As, Bs, acc);

  int w = threadIdx.x >> 6, l = threadIdx.x & 63;
  int q = l & 15, g = l >> 4;
  int wr = w >> 1, wc = w & 1;
#pragma unroll
  for (int m = 0; m < 4; ++m) {
    int row = row0 + wr * 64 + m * 16 + q;
#pragma unroll
    for (int n = 0; n < 4; ++n) {
      int col = col0 + wc * 64 + n * 16 + g * 4;
      f32x4 bv = *reinterpret_cast<const f32x4*>(&bias[col]);
      f32x4 ov = acc[m][n] + bv;
      *reinterpret_cast<f32x4*>(&out[(size_t)row * DM + col]) = ov;
    }
  }
}

// ---------- flash attention v12 (validated, 179.4-us config): 32 q-rows/wave ----------
__global__ __launch_bounds__(256, 4) void k_attn12(const short* __restrict__ qw,
                                                   const short* __restrict__ kw,
                                                   const short* __restrict__ vtw,
                                                   short* __restrict__ ao) {
  __shared__ __align__(16) short lds[2][2][4096];   // 32 KiB

  int bid = blockIdx.x;                       // 768 blocks, %8==0
  int swz = (bid & 7) * 96 + (bid >> 3);      // XCD-contiguous: each XCD gets 3 bh
  int bh = swz >> 5;
  int qchunk = swz & 31;

  int w = threadIdx.x >> 6, l = threadIdx.x & 63;
  int q = l & 15, g = l >> 4;

  const short* Kg = kw + (size_t)bh * SEQ * HD;
  const short* Vg = vtw + (size_t)bh * HD * SEQ;

  int ss = (l & 7) ^ (l >> 3) ^ ((w & 1) << 2);
  int rst = w * 8 + (l >> 3);

  int qbase = qchunk * 128 + w * 32;
  s16x8 qf[2][2];                             // [qt2][kh]
#pragma unroll
  for (int qt2 = 0; qt2 < 2; ++qt2)
#pragma unroll
    for (int kh = 0; kh < 2; ++kh)
      qf[qt2][kh] = *reinterpret_cast<const s16x8*>(
          qw + ((size_t)bh * SEQ + qbase + qt2 * 16 + q) * HD + kh * 32 + g * 8);

  // ones A-fragment for the row-sum MFMA: A[0][k]=1 (lanes q==0), else 0
  s16x8 ones;
  {
    short o1 = (q == 0) ? (short)0x3F80 : (short)0;
#pragma unroll
    for (int i = 0; i < 8; ++i) ones[i] = o1;
  }

  f32x4 o[2][4] = {};
  f32x4 lsa[2] = {};                          // row-sum rides in C-row 0 (lanes g==0, reg 0)

#define STAGE(buf, t)                                                              \
  {                                                                                \
    int key0 = (t) * 64;                                                           \
    _Pragma("unroll")                                                              \
    for (int i = 0; i < 2; ++i) {                                                  \
      const short* gk = Kg + (size_t)(key0 + i * 32 + rst) * HD + ss * 8;          \
      __builtin_amdgcn_global_load_lds((gas_t)gk,                                  \
          (las_t)&lds[buf][0][i * 2048 + w * 512], 16, 0, 0);                      \
      const short* gv = Vg + (size_t)(i * 32 + rst) * SEQ + key0 + ss * 8;         \
      __builtin_amdgcn_global_load_lds((gas_t)gv,                                  \
          (las_t)&lds[buf][1][i * 2048 + w * 512], 16, 0, 0);                      \
    }                                                                              \
  }

  // one tile: stage (optionally) into NXT, compute from CUR (static), barrier
#define TBODY(CUR, NXT, tt, DO_STAGE)                                              \
  {                                                                                \
    if (DO_STAGE) STAGE(NXT, (tt) + 1);                                            \
    f32x4 s[2][2][2] = {};   /* [c half][ab tile][qt2] */                          \
    __builtin_amdgcn_s_setprio(1);                                                 \
    _Pragma("unroll")                                                              \
    for (int c = 0; c < 2; ++c)                                                    \
      _Pragma("unroll")                                                            \
      for (int ab = 0; ab < 2; ++ab) {                                             \
        int R = c * 32 + ab * 4 + ((q >> 2) << 3) + (q & 3);                       \
        int sw = (R & 7) ^ (((R >> 3) & 1) << 2);                                  \
        _Pragma("unroll")                                                          \
        for (int kh = 0; kh < 2; ++kh) {                                           \
          int slot = (kh * 4 + g) ^ sw;                                            \
          s16x8 af = *reinterpret_cast<const s16x8*>(                              \
              &lds[CUR][0][R * 64 + slot * 8]);                                    \
          s[c][ab][0] = MFMA(af, qf[0][kh], s[c][ab][0]);                          \
          s[c][ab][1] = MFMA(af, qf[1][kh], s[c][ab][1]);                          \
        }                                                                          \
      }                                                                            \
    __builtin_amdgcn_s_setprio(0);                                                 \
    i32x4 pv[2][2];          /* packed bf16 P, [c][qt2] */                         \
    _Pragma("unroll")                                                              \
    for (int qt2 = 0; qt2 < 2; ++qt2) {                                            \
      unsigned u[16];                                                              \
      _Pragma("unroll")                                                            \
      for (int i = 0; i < 16; ++i)                                                 \
        u[i] = __float_as_uint(exp2v(s[i >> 3][(i >> 2) & 1][qt2][i & 3]));        \
      _Pragma("unroll")                                                            \
      for (int c = 0; c < 2; ++c)                                                  \
        _Pragma("unroll")                                                          \
        for (int j = 0; j < 4; ++j)                                                \
          pv[c][qt2][j] = (int)__builtin_amdgcn_perm(u[c * 8 + 2 * j + 1],         \
                                                     u[c * 8 + 2 * j],             \
                                                     0x07060302u);                 \
    }                                                                              \
    __builtin_amdgcn_s_setprio(1);                                                 \
    _Pragma("unroll")                                                              \
    for (int c = 0; c < 2; ++c) {                                                  \
      s16x8 p0 = __builtin_bit_cast(s16x8, pv[c][0]);                              \
      s16x8 p1 = __builtin_bit_cast(s16x8, pv[c][1]);                              \
      _Pragma("unroll")                                                            \
      for (int dt = 0; dt < 4; ++dt) {                                             \
        int R = dt * 16 + q;                                                       \
        int sw = (R & 7) ^ (((R >> 3) & 1) << 2);                                  \
        int slot = (c * 4 + g) ^ sw;                                               \
        s16x8 vf = *reinterpret_cast<const s16x8*>(                                \
            &lds[CUR][1][R * 64 + slot * 8]);                                      \
        o[0][dt] = MFMA(vf, p0, o[0][dt]);                                         \
        o[1][dt] = MFMA(vf, p1, o[1][dt]);                                         \
      }                                                                            \
      lsa[0] = MFMA(ones, p0, lsa[0]);                                             \
      lsa[1] = MFMA(ones, p1, lsa[1]);                                             \
    }                                                                              \
    __builtin_amdgcn_s_setprio(0);                                                 \
    __syncthreads();                                                               \
  }

  STAGE(0, 0);
  __syncthreads();

  for (int t = 0; t < SEQ / 64 - 2; t += 2) {
    TBODY(0, 1, t, true);
    TBODY(1, 0, t + 1, true);
  }
  TBODY(0, 1, SEQ / 64 - 2, true);
  TBODY(1, 0, SEQ / 64 - 1, false);
#undef TBODY
#undef STAGE

  // ---- epilogue: broadcast row-sums from lanes (q, g=0) ----
  int b = bh / NH, h = bh % NH;
  float ls0 = __shfl(lsa[0][0], q);
  float ls1 = __shfl(lsa[1][0], q);
  float inv[2] = { 1.f / ls0, 1.f / ls1 };
#pragma unroll
  for (int qt2 = 0; qt2 < 2; ++qt2) {
    size_t row = (size_t)b * SEQ + qbase + qt2 * 16 + q;
    short* op = ao + row * DM + h * HD;
#pragma unroll
    for (int dt = 0; dt < 4; ++dt) {
      short4 ov = { f2bf(o[qt2][dt][0] * inv[qt2]), f2bf(o[qt2][dt][1] * inv[qt2]),
                    f2bf(o[qt2][dt][2] * inv[qt2]), f2bf(o[qt2][dt][3] * inv[qt2]) };
      *reinterpret_cast<short4*>(op + dt * 16 + g * 4) = ov;
    }
  }
}

extern "C" void kernel_launch(void* const* d_in, const int* in_sizes, int n_in,
                              void* d_out, int out_size, void* d_ws, size_t ws_size,
                              hipStream_t stream) {
  const float* x      = (const float*)d_in[0];
  const float* w_qkv  = (const float*)d_in[1];
  const float* w_proj = (const float*)d_in[2];
  const float* b_proj = (const float*)d_in[3];
  float* out = (float*)d_out;

  char* p = (char*)d_ws;
  auto take = [&](size_t bytes) { char* r = p; p += (bytes + 255) & ~(size_t)255; return r; };
  short* xb     = (short*)take((size_t)ROWS * DM * 2);
  short* wtqkv  = (short*)take((size_t)3 * DM * DM * 2);
  short* wtproj = (short*)take((size_t)DM * DM * 2);
  short* qw     = (short*)take((size_t)NB * NH * SEQ * HD * 2);
  short* kw     = (short*)take((size_t)NB * NH * SEQ * HD * 2);
  short* vtw    = (short*)take((size_t)NB * NH * HD * SEQ * 2);
  short* ao     = (short*)take((size_t)ROWS * DM * 2);

  k_prep<<<NC4 + NT1 + NT2, 256, 0, stream>>>(x, xb, w_qkv, wtqkv, w_proj, wtproj);
  k_gemm_qkv2<<<64 * 18, 256, 0, stream>>>(xb, wtqkv, qw, kw, vtw);
  k_attn12<<<NB * NH * (SEQ / 128), 256, 0, stream>>>(qw, kw, vtw, ao);
  k_gemm_proj2<<<64 * 6, 256, 0, stream>>>(ao, wtproj, b_proj, out);
}

// Round 18
// 175.816 us; speedup vs baseline: 1.0946x; 1.0068x over previous
//
#include <hip/hip_runtime.h>
#include <hip/hip_bf16.h>

typedef __attribute__((ext_vector_type(4))) float f32x4;
typedef __attribute__((ext_vector_type(4))) int i32x4;
typedef __attribute__((ext_vector_type(8))) short s16x8;

static constexpr int NB = 2, NH = 12, SEQ = 4096, DM = 768, HD = 64;
static constexpr int ROWS = NB * SEQ;              // 8192
// Q is pre-scaled by SCALE*log2(e) in the QKV epilogue -> scores arrive in log2 domain
static constexpr float QSC = 0.125f * 1.44269504f; // 0.18033688

#define MFMA(a, b, c) __builtin_amdgcn_mfma_f32_16x16x32_bf16((a), (b), (c), 0, 0, 0)

typedef const void __attribute__((address_space(1)))* gas_t;
typedef void __attribute__((address_space(3)))* las_t;

__device__ __forceinline__ short f2bf(float f) {
  union { float f; unsigned u; } v; v.f = f;
  unsigned r = v.u + 0x7fffu + ((v.u >> 16) & 1u);   // round-to-nearest-even
  return (short)(r >> 16);
}

__device__ __forceinline__ float exp2v(float x) {    // raw v_exp_f32 (2^x)
  float r; asm("v_exp_f32 %0, %1" : "=v"(r) : "v"(x)); return r;
}

// ---------- fused prep: cast x -> bf16, transpose-cast both weight matrices ----------
static constexpr int NC4 = ROWS * DM / 4 / 256;        // 6144 blocks for cast
static constexpr int NT1 = (DM / 32) * (3 * DM / 32);  // 1728 blocks for w_qkv^T
static constexpr int NT2 = (DM / 32) * (DM / 32);      // 576 blocks for w_proj^T

__device__ __forceinline__ void tcast_body(const float* __restrict__ in,
                                           short* __restrict__ out, int r, int c,
                                           int bid, short tile[32][33]) {
  int tpc = c >> 5;
  int by = bid / tpc, bx = bid % tpc;
  int tx = threadIdx.x & 31, ty = threadIdx.x >> 5;   // 32 x 8
#pragma unroll
  for (int i = 0; i < 4; ++i)
    tile[ty + i * 8][tx] = f2bf(in[(size_t)(by * 32 + ty + i * 8) * c + bx * 32 + tx]);
  __syncthreads();
#pragma unroll
  for (int i = 0; i < 4; ++i)
    out[(size_t)(bx * 32 + ty + i * 8) * r + by * 32 + tx] = tile[tx][ty + i * 8];
}

__global__ __launch_bounds__(256) void k_prep(const float* __restrict__ x,
                                              short* __restrict__ xb,
                                              const float* __restrict__ wqkv,
                                              short* __restrict__ wtqkv,
                                              const float* __restrict__ wproj,
                                              short* __restrict__ wtproj) {
  __shared__ short tile[32][33];
  int bid = blockIdx.x;
  if (bid < NC4) {
    int i = bid * 256 + threadIdx.x;
    float4 v = reinterpret_cast<const float4*>(x)[i];
    short4 o = { f2bf(v.x), f2bf(v.y), f2bf(v.z), f2bf(v.w) };
    reinterpret_cast<short4*>(xb)[i] = o;
  } else if (bid < NC4 + NT1) {
    tcast_body(wqkv, wtqkv, DM, 3 * DM, bid - NC4, tile);
  } else {
    tcast_body(wproj, wtproj, DM, DM, bid - NC4 - NT1, tile);
  }
}

// ---------- 128x128-tile 2-phase GEMM core, C^T fragments ----------
__device__ __forceinline__ void gemm128(const short* __restrict__ A,
                                        const short* __restrict__ Bt,
                                        int K, int row0, int col0,
                                        short As[2][4096], short Bs[2][4096],
                                        f32x4 acc[4][4]) {
  int w = threadIdx.x >> 6, l = threadIdx.x & 63;
  int q = l & 15, g = l >> 4;
  int wr = w >> 1, wc = w & 1;
  int sr = w * 16 + (l >> 2);
  int sc = (l & 3) * 8;

#define STG(buf, k0)                                                           \
  {                                                                            \
    _Pragma("unroll")                                                          \
    for (int i = 0; i < 2; ++i) {                                              \
      __builtin_amdgcn_global_load_lds(                                        \
          (gas_t)(A + (size_t)(row0 + i * 64 + sr) * K + (k0) + sc),           \
          (las_t)&As[buf][i * 2048 + w * 512], 16, 0, 0);                      \
      __builtin_amdgcn_global_load_lds(                                        \
          (gas_t)(Bt + (size_t)(col0 + i * 64 + sr) * K + (k0) + sc),          \
          (las_t)&Bs[buf][i * 2048 + w * 512], 16, 0, 0);                      \
    }                                                                          \
  }

  STG(0, 0);
  __syncthreads();
  int cur = 0;
  for (int k0 = 0; k0 < K; k0 += 32) {
    if (k0 + 32 < K) STG(cur ^ 1, k0 + 32);
    s16x8 af[4], bf[4];
#pragma unroll
    for (int m = 0; m < 4; ++m)
      af[m] = *reinterpret_cast<const s16x8*>(&As[cur][(wr * 64 + m * 16 + q) * 32 + g * 8]);
#pragma unroll
    for (int n = 0; n < 4; ++n)
      bf[n] = *reinterpret_cast<const s16x8*>(&Bs[cur][(wc * 64 + n * 16 + q) * 32 + g * 8]);
#pragma unroll
    for (int m = 0; m < 4; ++m)
#pragma unroll
      for (int n = 0; n < 4; ++n)
        acc[m][n] = MFMA(bf[n], af[m], acc[m][n]);   // swapped: C^T fragments
    __syncthreads();
    cur ^= 1;
  }
#undef STG
}

// ---------- QKV GEMM -> Q (pre-scaled), K row-major [bh][n][64], V^T [bh][64][n] ----------
__global__ __launch_bounds__(256) void k_gemm_qkv2(const short* __restrict__ xb,
                                                   const short* __restrict__ wt,  // [2304][768]
                                                   short* __restrict__ qw,
                                                   short* __restrict__ kw,
                                                   short* __restrict__ vtw) {
  __shared__ __align__(16) short As[2][4096], Bs[2][4096];
  int bid = blockIdx.x;                        // 1152 blocks, %8==0
  int swz = (bid & 7) * 144 + (bid >> 3);
  int brow = swz / 18, bcol = swz % 18;
  int row0 = brow * 128, col0 = bcol * 128;
  f32x4 acc[4][4] = {};
  gemm128(xb, wt, DM, row0, col0, As, Bs, acc);

  int w = threadIdx.x >> 6, l = threadIdx.x & 63;
  int q = l & 15, g = l >> 4;
  int wr = w >> 1, wc = w & 1;
  int cb = col0 + wc * 64;
  int which = cb / DM, h = (cb % DM) >> 6;
  int rowb = row0 + wr * 64;
  int b = rowb >> 12;
  int bh = b * NH + h;
#pragma unroll
  for (int m = 0; m < 4; ++m) {
    int nseq = (rowb & 4095) + m * 16 + q;     // seq row (fixed per m)
#pragma unroll
    for (int n = 0; n < 4; ++n) {
      int d = n * 16 + g * 4;                  // 4 consecutive d in acc[m][n][0..3]
      if (which == 2) {
#pragma unroll
        for (int r = 0; r < 4; ++r)
          vtw[((size_t)bh * HD + d + r) * SEQ + nseq] = f2bf(acc[m][n][r]);
      } else {
        short* dst = (which == 0) ? qw : kw;
        float sc = (which == 0) ? QSC : 1.f;
        short4 ov = { f2bf(acc[m][n][0] * sc), f2bf(acc[m][n][1] * sc),
                      f2bf(acc[m][n][2] * sc), f2bf(acc[m][n][3] * sc) };
        *reinterpret_cast<short4*>(&dst[((size_t)bh * SEQ + nseq) * HD + d]) = ov;
      }
    }
  }
}

// ---------- proj GEMM + bias -> fp32 out (float4 stores) ----------
__global__ __launch_bounds__(256) void k_gemm_proj2(const short* __restrict__ aob,
                                                    const short* __restrict__ wt,   // [768][768]
                                                    const float* __restrict__ bias,
                                                    float* __restrict__ out) {
  __shared__ __align__(16) short As[2][4096], Bs[2][4096];
  int bid = blockIdx.x;                        // 384 blocks, %8==0
  int swz = (bid & 7) * 48 + (bid >> 3);
  int brow = swz / 6, bcol = swz % 6;
  int row0 = brow * 128, col0 = bcol * 128;
  f32x4 acc[4][4] = {};
  gemm128(aob, wt, DM, row0, col0, As, Bs, acc);

  int w = threadIdx.x >> 6, l = threadIdx.x & 63;
  int q = l & 15, g = l >> 4;
  int wr = w >> 1, wc = w & 1;
#pragma unroll
  for (int m = 0; m < 4; ++m) {
    int row = row0 + wr * 64 + m * 16 + q;
#pragma unroll
    for (int n = 0; n < 4; ++n) {
      int col = col0 + wc * 64 + n * 16 + g * 4;
      f32x4 bv = *reinterpret_cast<const f32x4*>(&bias[col]);
      f32x4 ov = acc[m][n] + bv;
      *reinterpret_cast<f32x4*>(&out[(size_t)row * DM + col]) = ov;
    }
  }
}

// ---------- flash attention v15: 3-buffer rotation + K-fragment register prefetch ----------
// With 2 buffers, tile t+1's K ds_reads must wait for tile t's barrier. With 3
// buffers, buf (t+1)%3 was staged during t-1 (valid all of tile t), so tile t
// prefetches t+1's 8 K-fragments into registers during softmax/PV, removing the
// ds_read latency from the chain head. Buf (t+1)%3 is re-staged only at t+2
// (after t+1's barrier) -> no race; barrier pattern unchanged (1 per tile).
__global__ __launch_bounds__(256, 3) void k_attn15(const short* __restrict__ qw,
                                                   const short* __restrict__ kw,
                                                   const short* __restrict__ vtw,
                                                   short* __restrict__ ao) {
  __shared__ __align__(16) short lds[3][2][4096];   // 48 KiB

  int bid = blockIdx.x;                       // 768 blocks, %8==0
  int swz = (bid & 7) * 96 + (bid >> 3);      // XCD-contiguous: each XCD gets 3 bh
  int bh = swz >> 5;
  int qchunk = swz & 31;

  int w = threadIdx.x >> 6, l = threadIdx.x & 63;
  int q = l & 15, g = l >> 4;

  const short* Kg = kw + (size_t)bh * SEQ * HD;
  const short* Vg = vtw + (size_t)bh * HD * SEQ;

  int ss = (l & 7) ^ (l >> 3) ^ ((w & 1) << 2);
  int rst = w * 8 + (l >> 3);

  int qbase = qchunk * 128 + w * 32;
  s16x8 qf[2][2];                             // [qt2][kh]
#pragma unroll
  for (int qt2 = 0; qt2 < 2; ++qt2)
#pragma unroll
    for (int kh = 0; kh < 2; ++kh)
      qf[qt2][kh] = *reinterpret_cast<const s16x8*>(
          qw + ((size_t)bh * SEQ + qbase + qt2 * 16 + q) * HD + kh * 32 + g * 8);

  // ones A-fragment for the row-sum MFMA: A[0][k]=1 (lanes q==0), else 0
  s16x8 ones;
  {
    short o1 = (q == 0) ? (short)0x3F80 : (short)0;
#pragma unroll
    for (int i = 0; i < 8; ++i) ones[i] = o1;
  }

  f32x4 o[2][4] = {};
  f32x4 lsa[2] = {};                          // row-sum rides in C-row 0 (lanes g==0, reg 0)
  s16x8 kf[8];                                // prefetched K frags [c*4 + ab*2 + kh]

#define STAGE(buf, t)                                                              \
  {                                                                                \
    int key0 = (t) * 64;                                                           \
    _Pragma("unroll")                                                              \
    for (int i = 0; i < 2; ++i) {                                                  \
      const short* gk = Kg + (size_t)(key0 + i * 32 + rst) * HD + ss * 8;          \
      __builtin_amdgcn_global_load_lds((gas_t)gk,                                  \
          (las_t)&lds[buf][0][i * 2048 + w * 512], 16, 0, 0);                      \
      const short* gv = Vg + (size_t)(i * 32 + rst) * SEQ + key0 + ss * 8;         \
      __builtin_amdgcn_global_load_lds((gas_t)gv,                                  \
          (las_t)&lds[buf][1][i * 2048 + w * 512], 16, 0, 0);                      \
    }                                                                              \
  }

  // load the 8 K fragments for a tile from buffer BUF into kf[]
#define LDK(BUF)                                                                   \
  {                                                                                \
    _Pragma("unroll")                                                              \
    for (int c = 0; c < 2; ++c)                                                    \
      _Pragma("unroll")                                                            \
      for (int ab = 0; ab < 2; ++ab) {                                             \
        int R = c * 32 + ab * 4 + ((q >> 2) << 3) + (q & 3);                       \
        int sw = (R & 7) ^ (((R >> 3) & 1) << 2);                                  \
        _Pragma("unroll")                                                          \
        for (int kh = 0; kh < 2; ++kh) {                                           \
          int slot = (kh * 4 + g) ^ sw;                                            \
          kf[c * 4 + ab * 2 + kh] = *reinterpret_cast<const s16x8*>(               \
              &lds[BUF][0][R * 64 + slot * 8]);                                    \
        }                                                                          \
      }                                                                            \
  }

  // one tile: QK from prefetched kf; stage t+2 into BC; prefetch t+1's K from BN;
  // PV from BCUR's V; barrier.
#define TBODY(BCUR, BN, BC, tt)                                                    \
  {                                                                                \
    if ((tt) + 2 < SEQ / 64) STAGE(BC, (tt) + 2);                                  \
    f32x4 s[2][2][2] = {};   /* [c half][ab tile][qt2] */                          \
    __builtin_amdgcn_s_setprio(1);                                                 \
    _Pragma("unroll")                                                              \
    for (int c = 0; c < 2; ++c)                                                    \
      _Pragma("unroll")                                                            \
      for (int ab = 0; ab < 2; ++ab)                                               \
        _Pragma("unroll")                                                          \
        for (int kh = 0; kh < 2; ++kh) {                                           \
          s16x8 af = kf[c * 4 + ab * 2 + kh];                                      \
          s[c][ab][0] = MFMA(af, qf[0][kh], s[c][ab][0]);                          \
          s[c][ab][1] = MFMA(af, qf[1][kh], s[c][ab][1]);                          \
        }                                                                          \
    __builtin_amdgcn_s_setprio(0);                                                 \
    if ((tt) + 1 < SEQ / 64) LDK(BN);                                              \
    i32x4 pv[2][2];          /* packed bf16 P, [c][qt2] */                         \
    _Pragma("unroll")                                                              \
    for (int qt2 = 0; qt2 < 2; ++qt2) {                                            \
      unsigned u[16];                                                              \
      _Pragma("unroll")                                                            \
      for (int i = 0; i < 16; ++i)                                                 \
        u[i] = __float_as_uint(exp2v(s[i >> 3][(i >> 2) & 1][qt2][i & 3]));        \
      _Pragma("unroll")                                                            \
      for (int c = 0; c < 2; ++c)                                                  \
        _Pragma("unroll")                                                          \
        for (int j = 0; j < 4; ++j)                                                \
          pv[c][qt2][j] = (int)__builtin_amdgcn_perm(u[c * 8 + 2 * j + 1],         \
                                                     u[c * 8 + 2 * j],             \
                                                     0x07060302u);                 \
    }                                                                              \
    __builtin_amdgcn_s_setprio(1);                                                 \
    _Pragma("unroll")                                                              \
    for (int c = 0; c < 2; ++c) {                                                  \
      s16x8 p0 = __builtin_bit_cast(s16x8, pv[c][0]);                              \
      s16x8 p1 = __builtin_bit_cast(s16x8, pv[c][1]);                              \
      _Pragma("unroll")                                                            \
      for (int dt = 0; dt < 4; ++dt) {                                             \
        int R = dt * 16 + q;                                                       \
        int sw = (R & 7) ^ (((R >> 3) & 1) << 2);                                  \
        int slot = (c * 4 + g) ^ sw;                                               \
        s16x8 vf = *reinterpret_cast<const s16x8*>(                                \
            &lds[BCUR][1][R * 64 + slot * 8]);                                     \
        o[0][dt] = MFMA(vf, p0, o[0][dt]);                                         \
        o[1][dt] = MFMA(vf, p1, o[1][dt]);                                         \
      }                                                                            \
      lsa[0] = MFMA(ones, p0, lsa[0]);                                             \
      lsa[1] = MFMA(ones, p1, lsa[1]);                                             \
    }                                                                              \
    __builtin_amdgcn_s_setprio(0);                                                 \
    __syncthreads();                                                               \
  }

  STAGE(0, 0);
  STAGE(1, 1);
  __syncthreads();          // drains both stages: buffers 0 AND 1 valid
  LDK(0);                   // K frags for tile 0

  for (int t = 0; t < SEQ / 64 - 1; t += 3) {   // 21 iterations: tiles 0..62
    TBODY(0, 1, 2, t);
    TBODY(1, 2, 0, t + 1);
    TBODY(2, 0, 1, t + 2);
  }
  TBODY(0, 1, 2, SEQ / 64 - 1);                 // tile 63 (63%3==0)
#undef TBODY
#undef LDK
#undef STAGE

  // ---- epilogue: broadcast row-sums from lanes (q, g=0) ----
  int b = bh / NH, h = bh % NH;
  float ls0 = __shfl(lsa[0][0], q);
  float ls1 = __shfl(lsa[1][0], q);
  float inv[2] = { 1.f / ls0, 1.f / ls1 };
#pragma unroll
  for (int qt2 = 0; qt2 < 2; ++qt2) {
    size_t row = (size_t)b * SEQ + qbase + qt2 * 16 + q;
    short* op = ao + row * DM + h * HD;
#pragma unroll
    for (int dt = 0; dt < 4; ++dt) {
      short4 ov = { f2bf(o[qt2][dt][0] * inv[qt2]), f2bf(o[qt2][dt][1] * inv[qt2]),
                    f2bf(o[qt2][dt][2] * inv[qt2]), f2bf(o[qt2][dt][3] * inv[qt2]) };
      *reinterpret_cast<short4*>(op + dt * 16 + g * 4) = ov;
    }
  }
}

extern "C" void kernel_launch(void* const* d_in, const int* in_sizes, int n_in,
                              void* d_out, int out_size, void* d_ws, size_t ws_size,
                              hipStream_t stream) {
  const float* x      = (const float*)d_in[0];
  const float* w_qkv  = (const float*)d_in[1];
  const float* w_proj = (const float*)d_in[2];
  const float* b_proj = (const float*)d_in[3];
  float* out = (float*)d_out;

  char* p = (char*)d_ws;
  auto take = [&](size_t bytes) { char* r = p; p += (bytes + 255) & ~(size_t)255; return r; };
  short* xb     = (short*)take((size_t)ROWS * DM * 2);
  short* wtqkv  = (short*)take((size_t)3 * DM * DM * 2);
  short* wtproj = (short*)take((size_t)DM * DM * 2);
  short* qw     = (short*)take((size_t)NB * NH * SEQ * HD * 2);
  short* kw     = (short*)take((size_t)NB * NH * SEQ * HD * 2);
  short* vtw    = (short*)take((size_t)NB * NH * HD * SEQ * 2);
  short* ao     = (short*)take((size_t)ROWS * DM * 2);

  k_prep<<<NC4 + NT1 + NT2, 256, 0, stream>>>(x, xb, w_qkv, wtqkv, w_proj, wtproj);
  k_gemm_qkv2<<<64 * 18, 256, 0, stream>>>(xb, wtqkv, qw, kw, vtw);
  k_attn15<<<NB * NH * (SEQ / 128), 256, 0, stream>>>(qw, kw, vtw, ao);
  k_gemm_proj2<<<64 * 6, 256, 0, stream>>>(ao, wtproj, b_proj, out);
}